// Round 5
// baseline (653.322 us; speedup 1.0000x reference)
//
#include <hip/hip_runtime.h>
#include <cstdint>

typedef __attribute__((ext_vector_type(8))) short short8;
typedef __attribute__((ext_vector_type(4))) float floatx4;
typedef unsigned int uint;

#define TSEQ 256
#define TDEC 180
#define NIN  6
#define GROWS 16
#define NBLK (4096 / GROWS)
#define RS0 104   // s0 row stride (shorts): cols 0..63 h0, 64..95 x|0, 96..103 pad
#define RS1 72    // s1 row stride

// split fp32 into hi/lo bf16 (truncation): x ~= hi + lo, err ~2^-16*|x|
__device__ __forceinline__ void split2(float x, uint16_t &h, uint16_t &l) {
  uint32_t u = __float_as_uint(x);
  h = (uint16_t)(u >> 16);
  float hf = __uint_as_float(u & 0xffff0000u);
  l = (uint16_t)(__float_as_uint(x - hf) >> 16);
}

__device__ __forceinline__ floatx4 mfma16(short8 a, short8 b, floatx4 c) {
  return __builtin_amdgcn_mfma_f32_16x16x32_bf16(a, b, c, 0, 0, 0);
}

__device__ __forceinline__ float sigm(float v) {
  return __builtin_amdgcn_rcpf(1.0f + __builtin_amdgcn_exp2f(-1.4426950408889634f * v));
}
__device__ __forceinline__ float tanh_fast(float v) {
  return 2.0f * __builtin_amdgcn_rcpf(1.0f + __builtin_amdgcn_exp2f(-2.8853900817779268f * v)) - 1.0f;
}

__device__ __forceinline__ short8 ld8(const uint16_t* p) { return *(const short8*)p; }

// one 2-kt source, 18 MFMAs into 6 accumulator chains:
// H-chains depth 2 (hi*hi), C-chains depth 4 (corrections)
#define ACC6(F0H,F0L,F1H,F1L, Wh, Wl, RH,RC,ZH,ZC,GH,GC) do {                              \
  RH = mfma16(F0H, Wh[0][0], RH); ZH = mfma16(F0H, Wh[1][0], ZH); GH = mfma16(F0H, Wh[2][0], GH); \
  RC = mfma16(F0L, Wh[0][0], RC); ZC = mfma16(F0L, Wh[1][0], ZC); GC = mfma16(F0L, Wh[2][0], GC); \
  RH = mfma16(F1H, Wh[0][1], RH); ZH = mfma16(F1H, Wh[1][1], ZH); GH = mfma16(F1H, Wh[2][1], GH); \
  RC = mfma16(F0H, Wl[0][0], RC); ZC = mfma16(F0H, Wl[1][0], ZC); GC = mfma16(F0H, Wl[2][0], GC); \
  RC = mfma16(F1L, Wh[0][1], RC); ZC = mfma16(F1L, Wh[1][1], ZC); GC = mfma16(F1L, Wh[2][1], GC); \
  RC = mfma16(F1H, Wl[0][1], RC); ZC = mfma16(F1H, Wl[1][1], ZC); GC = mfma16(F1H, Wl[2][1], GC); \
} while (0)

// one 1-kt source (x slot), 9 MFMAs: H depth 1, C depth 2
#define ACC6_1KT(FH,FL, Wh, Wl, RH,RC,ZH,ZC,GH,GC) do {                                    \
  RH = mfma16(FH, Wh[0][0], RH); ZH = mfma16(FH, Wh[1][0], ZH); GH = mfma16(FH, Wh[2][0], GH); \
  RC = mfma16(FL, Wh[0][0], RC); ZC = mfma16(FL, Wh[1][0], ZC); GC = mfma16(FL, Wh[2][0], GC); \
  RC = mfma16(FH, Wl[0][0], RC); ZC = mfma16(FH, Wl[1][0], ZC); GC = mfma16(FH, Wl[2][0], GC); \
} while (0)

// gate combine (merge H+C chains) + state update + split-bf16 h write
#define EPILOGUE(RH,RC,ZH,ZC, GIH,GIC, GHH,GHC, DSTH, DSTL, RS, PN) do {                   \
  _Pragma("unroll")                                                                        \
  for (int r4 = 0; r4 < 4; r4++) {                                                         \
    const float gr = sigm(RH[r4] + RC[r4]);                                                \
    const float gz = sigm(ZH[r4] + ZC[r4]);                                                \
    const float nn = tanh_fast((GIH[r4] + GIC[r4]) + gr * (GHH[r4] + GHC[r4]));            \
    const float hn = nn + gz * (hr[r4] - nn);                                              \
    hr[r4] = hn;                                                                           \
    uint16_t hh_, hl_; split2(hn, hh_, hl_);                                               \
    (DSTH)[(PN) * 16 * (RS) + (q * 4 + r4) * (RS) + u] = hh_;                              \
    (DSTL)[(PN) * 16 * (RS) + (q * 4 + r4) * (RS) + u] = hl_;                              \
  } } while (0)

__device__ __forceinline__ void pollge(const volatile uint* p4, uint need) {
  for (;;) {
    uint a = p4[0], b = p4[1], cc = p4[2], d = p4[3];
    uint mn = min(min(a, b), min(cc, d));
    if (mn >= need) break;       // tight spin: no s_sleep (wake < ~130 cyc)
  }
  asm volatile("" ::: "memory");   // no hoisting of data reads above the poll
}

__global__ void __launch_bounds__(512, 2)
gru_persist(const float* __restrict__ x,
            const float* __restrict__ eWih0, const float* __restrict__ eWhh0,
            const float* __restrict__ ebih0, const float* __restrict__ ebhh0,
            const float* __restrict__ eWih1, const float* __restrict__ eWhh1,
            const float* __restrict__ ebih1, const float* __restrict__ ebhh1,
            const float* __restrict__ dWih0, const float* __restrict__ dWhh0,
            const float* __restrict__ dbih0, const float* __restrict__ dbhh0,
            const float* __restrict__ dWih1, const float* __restrict__ dWhh1,
            const float* __restrict__ dbih1, const float* __restrict__ dbhh1,
            const float* __restrict__ outW, const float* __restrict__ outB,
            float* __restrict__ out)
{
  __shared__ __align__(16) uint16_t s0h[2][16][RS0], s0l[2][16][RS0];
  __shared__ __align__(16) uint16_t s1h[2][16][RS1], s1l[2][16][RS1];
  __shared__ __align__(16) uint prog[8];   // [0..3]=A waves, [4..7]=B waves

  const int tid  = threadIdx.x;
  const bool isA = tid < 256;          // A = layer0 waves, B = layer1 waves
  const int wvL  = (tid >> 6) & 3;
  const int lane = tid & 63;
  const int c    = lane & 15;
  const int q    = lane >> 4;
  const int u    = wvL * 16 + c;
  const long base = (long)blockIdx.x * GROWS;

  const volatile uint* aprog = (const volatile uint*)&prog[0];
  const volatile uint* bprog = (const volatile uint*)&prog[4];
  volatile uint* myslot = (volatile uint*)&prog[(isA ? 0 : 4) + wvL];

  for (int i = tid; i < 2 * 16 * RS0; i += 512) { ((uint16_t*)s0h)[i] = 0; ((uint16_t*)s0l)[i] = 0; }
  for (int i = tid; i < 2 * 16 * RS1; i += 512) { ((uint16_t*)s1h)[i] = 0; ((uint16_t*)s1l)[i] = 0; }
  if (tid < 8) prog[tid] = 0;
  if (tid < GROWS * NIN) {  // x(0) -> s0[0]
    int m = tid / 6, i2 = tid - m * 6;
    uint16_t h, l; split2(x[(base + m) * (TSEQ * NIN) + i2], h, l);
    s0h[0][m][64 + i2] = h; s0l[0][m][64 + i2] = l;
  }

  short8 W1h[3][2], W1l[3][2];   // A: Whh0 | B: Wih1
  short8 W2h[3][2], W2l[3][2];   // A: [Wih0|0] (enc) / rank-1 fold (dec) | B: Whh1
  float hr[4] = {0, 0, 0, 0};

  auto loadW64 = [&](const float* W, short8 (&Dh)[3][2], short8 (&Dl)[3][2]) {
    #pragma unroll
    for (int s = 0; s < 3; s++) {
      const int n = (s * 4 + wvL) * 16 + c;
      #pragma unroll
      for (int kt = 0; kt < 2; kt++) {
        const int k0 = kt * 32 + q * 8;
        #pragma unroll
        for (int j = 0; j < 8; j++) {
          uint16_t h, l; split2(W[n * 64 + k0 + j], h, l);
          Dh[s][kt][j] = (short)h; Dl[s][kt][j] = (short)l;
        }
      }
    }
  };

  float cR, cZ, c3, c4;
  if (isA) {
    loadW64(eWhh0, W1h, W1l);
    #pragma unroll
    for (int s = 0; s < 3; s++) {
      const int n = (s * 4 + wvL) * 16 + c;
      #pragma unroll
      for (int kt = 0; kt < 2; kt++)
        #pragma unroll
        for (int j = 0; j < 8; j++) {
          float v = (kt == 0 && q == 0 && j < NIN) ? eWih0[n * NIN + j] : 0.0f;
          uint16_t h, l; split2(v, h, l);
          W2h[s][kt][j] = (short)h; W2l[s][kt][j] = (short)l;
        }
    }
    cR = ebih0[u] + ebhh0[u];
    cZ = ebih0[64 + u] + ebhh0[64 + u];
    c3 = ebhh0[128 + u];   // gh const (src1 = Whh0)
    c4 = ebih0[128 + u];   // gi const (src2 = x)
  } else {
    loadW64(eWih1, W1h, W1l); loadW64(eWhh1, W2h, W2l);
    cR = ebih1[u] + ebhh1[u];
    cZ = ebih1[64 + u] + ebhh1[64 + u];
    c3 = ebih1[128 + u];   // gi const (src1 = Wih1)
    c4 = ebhh1[128 + u];   // gh const (src2 = Whh1)
  }
  __syncthreads();   // last barrier: everything after uses the flag protocol

  if (isA) {
    // ---- x prefetch pipeline on wave A0, lanes 0..47, 2 slots each, depth 2 ----
    const bool doX = (wvL == 0) && (lane < 48);
    const float *px0 = nullptr, *px1 = nullptr;
    int xo0 = 0, xo1 = 0; float xn0 = 0.f, xn1 = 0.f;
    if (doX) {
      int s0_ = lane, s1_ = lane + 48;
      int m0 = s0_ / 6, i0 = s0_ - m0 * 6, m1 = s1_ / 6, i1 = s1_ - m1 * 6;
      px0 = x + (base + m0) * (TSEQ * NIN) + i0;
      px1 = x + (base + m1) * (TSEQ * NIN) + i1;
      xo0 = m0 * RS0 + 64 + i0; xo1 = m1 * RS0 + 64 + i1;
      xn0 = px0[NIN]; xn1 = px1[NIN];   // x(1)
    }
    // ================= encoder =================
    for (int i = 0; i < TSEQ; i += 2) {
      #pragma unroll
      for (int h2 = 0; h2 < 2; h2++) {
        const int i_ = i + h2, p = h2, pn = h2 ^ 1;
        pollge(aprog, (uint)i_);                       // peers done step i_-1 (incl. x(i_))
        const short8 a0h = ld8(&s0h[p][c][q * 8]),      a0l = ld8(&s0l[p][c][q * 8]);
        const short8 a1h = ld8(&s0h[p][c][32 + q * 8]), a1l = ld8(&s0l[p][c][32 + q * 8]);
        const short8 xfh = ld8(&s0h[p][c][64 + q * 8]), xfl = ld8(&s0l[p][c][64 + q * 8]);
        floatx4 rH = {cR, cR, cR, cR}, zH = {cZ, cZ, cZ, cZ};
        floatx4 ghH = {c3, c3, c3, c3}, giH = {c4, c4, c4, c4};
        floatx4 rC = {0, 0, 0, 0}, zC = {0, 0, 0, 0}, ghC = {0, 0, 0, 0}, giC = {0, 0, 0, 0};
        ACC6(a0h, a0l, a1h, a1l, W1h, W1l, rH, rC, zH, zC, ghH, ghC);     // Whh0.h0 -> gh
        ACC6_1KT(xfh, xfl, W2h, W2l, rH, rC, zH, zC, giH, giC);           // Wih0.x  -> gi
        pollge(bprog, (uint)(i_ > 0 ? i_ - 1 : 0));    // WAR: B consumed s0[pn] generation-2
        if (doX && i_ + 1 < TSEQ) {
          uint16_t hh, hl;
          split2(xn0, hh, hl); s0h[pn][0][xo0] = hh; s0l[pn][0][xo0] = hl;
          split2(xn1, hh, hl); s0h[pn][0][xo1] = hh; s0l[pn][0][xo1] = hl;
          if (i_ + 2 < TSEQ) { xn0 = px0[(i_ + 2) * NIN]; xn1 = px1[(i_ + 2) * NIN]; }
        }
        EPILOGUE(rH, rC, zH, zC, giH, giC, ghH, ghC, (&s0h[0][0][0]), (&s0l[0][0][0]), RS0, pn);
        asm volatile("s_waitcnt lgkmcnt(0)" ::: "memory");
        *myslot = (uint)(i_ + 1);
      }
    }
    // ================= decoder weights (fold) =================
    loadW64(dWhh0, W1h, W1l);
    const float ob = outB[0];
    #pragma unroll
    for (int s = 0; s < 3; s++) {
      const int n = (s * 4 + wvL) * 16 + c;
      const float wd = dWih0[n];
      #pragma unroll
      for (int kt = 0; kt < 2; kt++) {
        const int k0 = kt * 32 + q * 8;
        #pragma unroll
        for (int j = 0; j < 8; j++) {
          uint16_t h, l; split2(wd * outW[k0 + j], h, l);
          W2h[s][kt][j] = (short)h; W2l[s][kt][j] = (short)l;
        }
      }
    }
    const float bR0 = dbih0[u] + dbhh0[u];
    const float bZ0 = dbih0[64 + u] + dbhh0[64 + u];
    const float b30 = dbhh0[128 + u];
    const float b40 = dbih0[128 + u];
    cR = bR0 + dWih0[u] * ob;
    cZ = bZ0 + dWih0[64 + u] * ob;
    c3 = b30;
    c4 = b40 + dWih0[128 + u] * ob;
    // ================= decoder =================
    for (int i = TSEQ; i < TSEQ + TDEC; i += 2) {
      #pragma unroll
      for (int h2 = 0; h2 < 2; h2++) {
        const int i_ = i + h2, p = h2, pn = h2 ^ 1;
        const bool first = (i_ == TSEQ);
        pollge(aprog, (uint)i_);
        const short8 a0h = ld8(&s0h[p][c][q * 8]),      a0l = ld8(&s0l[p][c][q * 8]);
        const short8 a1h = ld8(&s0h[p][c][32 + q * 8]), a1l = ld8(&s0l[p][c][32 + q * 8]);
        const float vR = first ? bR0 : cR, vZ = first ? bZ0 : cZ, v4 = first ? b40 : c4;
        floatx4 rH = {vR, vR, vR, vR}, zH = {vZ, vZ, vZ, vZ};
        floatx4 ghH = {c3, c3, c3, c3}, giH = {v4, v4, v4, v4};
        floatx4 rC = {0, 0, 0, 0}, zC = {0, 0, 0, 0}, ghC = {0, 0, 0, 0}, giC = {0, 0, 0, 0};
        ACC6(a0h, a0l, a1h, a1l, W1h, W1l, rH, rC, zH, zC, ghH, ghC);     // Whh0.h0 -> gh
        pollge(bprog, (uint)(first ? i_ - 1 : i_));
        if (!first) {   // rank-1 head fold: W'.h1(d-1) -> r,z,gi
          const short8 b0h = ld8(&s1h[p][c][q * 8]),      b0l = ld8(&s1l[p][c][q * 8]);
          const short8 b1h = ld8(&s1h[p][c][32 + q * 8]), b1l = ld8(&s1l[p][c][32 + q * 8]);
          ACC6(b0h, b0l, b1h, b1l, W2h, W2l, rH, rC, zH, zC, giH, giC);
        }
        EPILOGUE(rH, rC, zH, zC, giH, giC, ghH, ghC, (&s0h[0][0][0]), (&s0l[0][0][0]), RS0, pn);
        asm volatile("s_waitcnt lgkmcnt(0)" ::: "memory");
        *myslot = (uint)(i_ + 1);
      }
    }
  } else {
    // =========================== group B: layer 1 ===========================
    const float ob = outB[0];
    float wk[2][8];
    #pragma unroll
    for (int kt = 0; kt < 2; kt++)
      #pragma unroll
      for (int j = 0; j < 8; j++) wk[kt][j] = outW[kt * 32 + q * 8 + j];

    for (int i = 0; i < TSEQ; i += 2) {
      #pragma unroll
      for (int h2 = 0; h2 < 2; h2++) {
        const int i_ = i + h2, p = h2, pn = h2 ^ 1;
        pollge(bprog, (uint)i_);                       // peers' h1(i_-1)
        const short8 f0h = ld8(&s1h[p][c][q * 8]),      f0l = ld8(&s1l[p][c][q * 8]);
        const short8 f1h = ld8(&s1h[p][c][32 + q * 8]), f1l = ld8(&s1l[p][c][32 + q * 8]);
        floatx4 rH = {cR, cR, cR, cR}, zH = {cZ, cZ, cZ, cZ};
        floatx4 giH = {c3, c3, c3, c3}, ghH = {c4, c4, c4, c4};
        floatx4 rC = {0, 0, 0, 0}, zC = {0, 0, 0, 0}, giC = {0, 0, 0, 0}, ghC = {0, 0, 0, 0};
        ACC6(f0h, f0l, f1h, f1l, W2h, W2l, rH, rC, zH, zC, ghH, ghC);     // Whh1.h1 -> gh
        pollge(aprog, (uint)(i_ + 1));                 // h0(i_) ready
        const short8 g0h = ld8(&s0h[pn][c][q * 8]),      g0l = ld8(&s0l[pn][c][q * 8]);
        const short8 g1h = ld8(&s0h[pn][c][32 + q * 8]), g1l = ld8(&s0l[pn][c][32 + q * 8]);
        ACC6(g0h, g0l, g1h, g1l, W1h, W1l, rH, rC, zH, zC, giH, giC);     // Wih1.h0 -> gi
        EPILOGUE(rH, rC, zH, zC, giH, giC, ghH, ghC, (&s1h[0][0][0]), (&s1l[0][0][0]), RS1, pn);
        asm volatile("s_waitcnt lgkmcnt(0)" ::: "memory");
        *myslot = (uint)(i_ + 1);
      }
    }
    loadW64(dWih1, W1h, W1l); loadW64(dWhh1, W2h, W2l);
    cR = dbih1[u] + dbhh1[u];
    cZ = dbih1[64 + u] + dbhh1[64 + u];
    c3 = dbih1[128 + u]; c4 = dbhh1[128 + u];
    for (int i = TSEQ; i < TSEQ + TDEC; i += 2) {
      #pragma unroll
      for (int h2 = 0; h2 < 2; h2++) {
        const int i_ = i + h2, p = h2, pn = h2 ^ 1;
        pollge(bprog, (uint)i_);
        const short8 f0h = ld8(&s1h[p][c][q * 8]),      f0l = ld8(&s1l[p][c][q * 8]);
        const short8 f1h = ld8(&s1h[p][c][32 + q * 8]), f1l = ld8(&s1l[p][c][32 + q * 8]);
        floatx4 rH = {cR, cR, cR, cR}, zH = {cZ, cZ, cZ, cZ};
        floatx4 giH = {c3, c3, c3, c3}, ghH = {c4, c4, c4, c4};
        floatx4 rC = {0, 0, 0, 0}, zC = {0, 0, 0, 0}, giC = {0, 0, 0, 0}, ghC = {0, 0, 0, 0};
        ACC6(f0h, f0l, f1h, f1l, W2h, W2l, rH, rC, zH, zC, ghH, ghC);     // Whh1.h1 -> gh
        if (wvL == 0 && i_ > TSEQ) {   // head: cv(d) from h1(i_-1) fragments (off critical path)
          float cv = 0.0f;
          #pragma unroll
          for (int j = 0; j < 8; j++) {
            cv = fmaf(__uint_as_float(((uint)(uint16_t)f0h[j]) << 16) +
                      __uint_as_float(((uint)(uint16_t)f0l[j]) << 16), wk[0][j], cv);
            cv = fmaf(__uint_as_float(((uint)(uint16_t)f1h[j]) << 16) +
                      __uint_as_float(((uint)(uint16_t)f1l[j]) << 16), wk[1][j], cv);
          }
          cv += __shfl_xor(cv, 16);
          cv += __shfl_xor(cv, 32);
          if (lane < 16) out[(base + lane) * TDEC + (i_ - TSEQ - 1)] = cv + ob;
        }
        pollge(aprog, (uint)(i_ + 1));
        const short8 g0h = ld8(&s0h[pn][c][q * 8]),      g0l = ld8(&s0l[pn][c][q * 8]);
        const short8 g1h = ld8(&s0h[pn][c][32 + q * 8]), g1l = ld8(&s0l[pn][c][32 + q * 8]);
        ACC6(g0h, g0l, g1h, g1l, W1h, W1l, rH, rC, zH, zC, giH, giC);     // Wih1.h0 -> gi
        EPILOGUE(rH, rC, zH, zC, giH, giC, ghH, ghC, (&s1h[0][0][0]), (&s1l[0][0][0]), RS1, pn);
        asm volatile("s_waitcnt lgkmcnt(0)" ::: "memory");
        *myslot = (uint)(i_ + 1);
      }
    }
    // final head value: cv(179) from h1(435) in s1[0]
    if (wvL == 0) {
      pollge(bprog, (uint)(TSEQ + TDEC));
      const short8 f0h = ld8(&s1h[0][c][q * 8]),      f0l = ld8(&s1l[0][c][q * 8]);
      const short8 f1h = ld8(&s1h[0][c][32 + q * 8]), f1l = ld8(&s1l[0][c][32 + q * 8]);
      float cv = 0.0f;
      #pragma unroll
      for (int j = 0; j < 8; j++) {
        cv = fmaf(__uint_as_float(((uint)(uint16_t)f0h[j]) << 16) +
                  __uint_as_float(((uint)(uint16_t)f0l[j]) << 16), wk[0][j], cv);
        cv = fmaf(__uint_as_float(((uint)(uint16_t)f1h[j]) << 16) +
                  __uint_as_float(((uint)(uint16_t)f1l[j]) << 16), wk[1][j], cv);
      }
      cv += __shfl_xor(cv, 16);
      cv += __shfl_xor(cv, 32);
      if (lane < 16) out[(base + lane) * TDEC + (TDEC - 1)] = cv + ob;
    }
  }
}

extern "C" void kernel_launch(void* const* d_in, const int* in_sizes, int n_in,
                              void* d_out, int out_size, void* d_ws, size_t ws_size,
                              hipStream_t stream) {
  (void)in_sizes; (void)n_in; (void)d_ws; (void)ws_size; (void)out_size;
  const float* x     = (const float*)d_in[0];
  const float* eWih0 = (const float*)d_in[1];
  const float* eWhh0 = (const float*)d_in[2];
  const float* ebih0 = (const float*)d_in[3];
  const float* ebhh0 = (const float*)d_in[4];
  const float* eWih1 = (const float*)d_in[5];
  const float* eWhh1 = (const float*)d_in[6];
  const float* ebih1 = (const float*)d_in[7];
  const float* ebhh1 = (const float*)d_in[8];
  const float* dWih0 = (const float*)d_in[9];
  const float* dWhh0 = (const float*)d_in[10];
  const float* dbih0 = (const float*)d_in[11];
  const float* dbhh0 = (const float*)d_in[12];
  const float* dWih1 = (const float*)d_in[13];
  const float* dWhh1 = (const float*)d_in[14];
  const float* dbih1 = (const float*)d_in[15];
  const float* dbhh1 = (const float*)d_in[16];
  const float* outW  = (const float*)d_in[17];
  const float* outB  = (const float*)d_in[18];
  hipLaunchKernelGGL(gru_persist, dim3(NBLK), dim3(512), 0, stream,
                     x, eWih0, eWhh0, ebih0, ebhh0, eWih1, eWhh1, ebih1, ebhh1,
                     dWih0, dWhh0, dbih0, dbhh0, dWih1, dWhh1, dbih1, dbhh1,
                     outW, outB, (float*)d_out);
}

// Round 6
// 474.587 us; speedup vs baseline: 1.3766x; 1.3766x over previous
//
#include <hip/hip_runtime.h>
#include <cstdint>

typedef _Float16 half8 __attribute__((ext_vector_type(8)));
typedef __attribute__((ext_vector_type(4))) float floatx4;
typedef unsigned int uint;

#define TSEQ 256
#define TDEC 180
#define NIN  6
#define GROWS 16
#define NBLK (4096 / GROWS)
#define RS0 104   // s0 row stride (halfs): cols 0..63 h0, 64..95 x|0, 96..103 pad (208B rows, 16B-aligned)
#define RS1 72    // s1 row stride (144B rows, 16B-aligned)

__device__ __forceinline__ floatx4 mfma16(half8 a, half8 b, floatx4 c) {
  return __builtin_amdgcn_mfma_f32_16x16x32_f16(a, b, c, 0, 0, 0);
}

__device__ __forceinline__ float sigm(float v) {
  return __builtin_amdgcn_rcpf(1.0f + __builtin_amdgcn_exp2f(-1.4426950408889634f * v));
}
__device__ __forceinline__ float tanh_fast(float v) {
  return 2.0f * __builtin_amdgcn_rcpf(1.0f + __builtin_amdgcn_exp2f(-2.8853900817779268f * v)) - 1.0f;
}

__device__ __forceinline__ half8 ldh8(const _Float16* p) { return *(const half8*)p; }

// single-term fp16: one 2-kt source -> 6 MFMAs into 3 gate accumulators
#define PASS2(F0, F1, r, z, g, W) do {                                  \
  r = mfma16(F0, W[0][0], r); z = mfma16(F0, W[1][0], z); g = mfma16(F0, W[2][0], g); \
  r = mfma16(F1, W[0][1], r); z = mfma16(F1, W[1][1], z); g = mfma16(F1, W[2][1], g); \
} while (0)

// 1-kt source (x slot) -> 3 MFMAs
#define PASS1(F0, r, z, g, W) do {                                      \
  r = mfma16(F0, W[0][0], r); z = mfma16(F0, W[1][0], z); g = mfma16(F0, W[2][0], g); \
} while (0)

__device__ __forceinline__ void pollge(const volatile uint* p4, uint need) {
  for (;;) {
    uint a = p4[0], b = p4[1], cc = p4[2], d = p4[3];
    uint mn = min(min(a, b), min(cc, d));
    if (mn >= need) break;
    __builtin_amdgcn_s_sleep(1);
  }
  asm volatile("" ::: "memory");   // no hoisting of data reads above the poll
}

__global__ void __launch_bounds__(512, 2)
gru_persist(const float* __restrict__ x,
            const float* __restrict__ eWih0, const float* __restrict__ eWhh0,
            const float* __restrict__ ebih0, const float* __restrict__ ebhh0,
            const float* __restrict__ eWih1, const float* __restrict__ eWhh1,
            const float* __restrict__ ebih1, const float* __restrict__ ebhh1,
            const float* __restrict__ dWih0, const float* __restrict__ dWhh0,
            const float* __restrict__ dbih0, const float* __restrict__ dbhh0,
            const float* __restrict__ dWih1, const float* __restrict__ dWhh1,
            const float* __restrict__ dbih1, const float* __restrict__ dbhh1,
            const float* __restrict__ outW, const float* __restrict__ outB,
            float* __restrict__ out)
{
  __shared__ __align__(16) _Float16 s0[2][16][RS0];
  __shared__ __align__(16) _Float16 s1[2][16][RS1];
  __shared__ __align__(16) uint prog[8];   // [0..3]=A waves, [4..7]=B waves

  const int tid  = threadIdx.x;
  const bool isA = tid < 256;          // A = layer0 waves, B = layer1 waves
  const int wvL  = (tid >> 6) & 3;
  const int lane = tid & 63;
  const int c    = lane & 15;
  const int q    = lane >> 4;
  const int u    = wvL * 16 + c;
  const long base = (long)blockIdx.x * GROWS;

  const volatile uint* aprog = (const volatile uint*)&prog[0];
  const volatile uint* bprog = (const volatile uint*)&prog[4];
  volatile uint* myslot = (volatile uint*)&prog[(isA ? 0 : 4) + wvL];

  for (int i = tid; i < 2 * 16 * RS0; i += 512) ((uint16_t*)s0)[i] = 0;
  for (int i = tid; i < 2 * 16 * RS1; i += 512) ((uint16_t*)s1)[i] = 0;
  if (tid < 8) prog[tid] = 0;
  if (tid < GROWS * NIN) {  // x(0) -> s0[0]
    int m = tid / 6, i2 = tid - m * 6;
    s0[0][m][64 + i2] = (_Float16)x[(base + m) * (TSEQ * NIN) + i2];
  }

  half8 W1[3][2];   // A: Whh0 | B: Wih1
  half8 W2[3][2];   // A: [Wih0|0] (enc) / rank-1 fold (dec) | B: Whh1
  float hr[4] = {0, 0, 0, 0};

  auto loadW64 = [&](const float* W, half8 (&D)[3][2]) {
    #pragma unroll
    for (int s = 0; s < 3; s++) {
      const int n = (s * 4 + wvL) * 16 + c;
      #pragma unroll
      for (int kt = 0; kt < 2; kt++) {
        const int k0 = kt * 32 + q * 8;
        #pragma unroll
        for (int j = 0; j < 8; j++) D[s][kt][j] = (_Float16)W[n * 64 + k0 + j];
      }
    }
  };

  float cR, cZ, c3, c4;
  if (isA) {
    loadW64(eWhh0, W1);
    #pragma unroll
    for (int s = 0; s < 3; s++) {
      const int n = (s * 4 + wvL) * 16 + c;
      #pragma unroll
      for (int kt = 0; kt < 2; kt++)
        #pragma unroll
        for (int j = 0; j < 8; j++) {
          float v = (kt == 0 && q == 0 && j < NIN) ? eWih0[n * NIN + j] : 0.0f;
          W2[s][kt][j] = (_Float16)v;
        }
    }
    cR = ebih0[u] + ebhh0[u];
    cZ = ebih0[64 + u] + ebhh0[64 + u];
    c3 = ebhh0[128 + u];   // gh const (src1 = Whh0)
    c4 = ebih0[128 + u];   // gi const (src2 = x)
  } else {
    loadW64(eWih1, W1); loadW64(eWhh1, W2);
    cR = ebih1[u] + ebhh1[u];
    cZ = ebih1[64 + u] + ebhh1[64 + u];
    c3 = ebih1[128 + u];   // gi const (src1 = Wih1)
    c4 = ebhh1[128 + u];   // gh const (src2 = Whh1)
  }
  __syncthreads();   // last barrier: everything after uses the flag protocol

  if (isA) {
    // ---- x prefetch pipeline on wave A0, lanes 0..47, 2 slots each, depth 2 ----
    const bool doX = (wvL == 0) && (lane < 48);
    const float *px0 = nullptr, *px1 = nullptr;
    int xo0 = 0, xo1 = 0; float xn0 = 0.f, xn1 = 0.f;
    if (doX) {
      int s0_ = lane, s1_ = lane + 48;
      int m0 = s0_ / 6, i0 = s0_ - m0 * 6, m1 = s1_ / 6, i1 = s1_ - m1 * 6;
      px0 = x + (base + m0) * (TSEQ * NIN) + i0;
      px1 = x + (base + m1) * (TSEQ * NIN) + i1;
      xo0 = m0 * RS0 + 64 + i0; xo1 = m1 * RS0 + 64 + i1;
      xn0 = px0[NIN]; xn1 = px1[NIN];   // x(1)
    }
    // ================= encoder =================
    for (int i = 0; i < TSEQ; i += 2) {
      #pragma unroll
      for (int h2 = 0; h2 < 2; h2++) {
        const int i_ = i + h2, p = h2, pn = h2 ^ 1;
        pollge(aprog, (uint)i_);                       // peers done step i_-1 (incl. x(i_))
        const half8 a0 = ldh8(&s0[p][c][q * 8]);
        const half8 a1 = ldh8(&s0[p][c][32 + q * 8]);
        const half8 xf = ldh8(&s0[p][c][64 + q * 8]);
        floatx4 aR = {cR, cR, cR, cR}, aZ = {cZ, cZ, cZ, cZ};
        floatx4 a3 = {c3, c3, c3, c3}, a4 = {c4, c4, c4, c4};
        PASS2(a0, a1, aR, aZ, a3, W1);                 // Whh0.h0 -> gh
        PASS1(xf, aR, aZ, a4, W2);                     // Wih0.x  -> gi
        pollge(bprog, (uint)(i_ > 0 ? i_ - 1 : 0));    // WAR: B consumed s0[pn] generation-2
        if (doX && i_ + 1 < TSEQ) {
          ((_Float16*)s0[pn])[xo0] = (_Float16)xn0;
          ((_Float16*)s0[pn])[xo1] = (_Float16)xn1;
          if (i_ + 2 < TSEQ) { xn0 = px0[(i_ + 2) * NIN]; xn1 = px1[(i_ + 2) * NIN]; }
        }
        #pragma unroll
        for (int r4 = 0; r4 < 4; r4++) {
          const float gr = sigm(aR[r4]);
          const float gz = sigm(aZ[r4]);
          const float nn = tanh_fast(a4[r4] + gr * a3[r4]);
          const float hn = nn + gz * (hr[r4] - nn);
          hr[r4] = hn;
          s0[pn][q * 4 + r4][u] = (_Float16)hn;
        }
        asm volatile("s_waitcnt lgkmcnt(0)" ::: "memory");
        *myslot = (uint)(i_ + 1);
      }
    }
    // ================= decoder weights (fold) =================
    loadW64(dWhh0, W1);
    const float ob = outB[0];
    #pragma unroll
    for (int s = 0; s < 3; s++) {
      const int n = (s * 4 + wvL) * 16 + c;
      const float wd = dWih0[n];
      #pragma unroll
      for (int kt = 0; kt < 2; kt++) {
        const int k0 = kt * 32 + q * 8;
        #pragma unroll
        for (int j = 0; j < 8; j++) W2[s][kt][j] = (_Float16)(wd * outW[k0 + j]);
      }
    }
    const float bR0 = dbih0[u] + dbhh0[u];
    const float bZ0 = dbih0[64 + u] + dbhh0[64 + u];
    const float b30 = dbhh0[128 + u];
    const float b40 = dbih0[128 + u];
    cR = bR0 + dWih0[u] * ob;
    cZ = bZ0 + dWih0[64 + u] * ob;
    c3 = b30;
    c4 = b40 + dWih0[128 + u] * ob;
    // ================= decoder =================
    for (int i = TSEQ; i < TSEQ + TDEC; i += 2) {
      #pragma unroll
      for (int h2 = 0; h2 < 2; h2++) {
        const int i_ = i + h2, p = h2, pn = h2 ^ 1;
        const bool first = (i_ == TSEQ);
        pollge(aprog, (uint)i_);
        const half8 a0 = ldh8(&s0[p][c][q * 8]);
        const half8 a1 = ldh8(&s0[p][c][32 + q * 8]);
        const float vR = first ? bR0 : cR, vZ = first ? bZ0 : cZ, v4 = first ? b40 : c4;
        floatx4 aR = {vR, vR, vR, vR}, aZ = {vZ, vZ, vZ, vZ};
        floatx4 a3 = {c3, c3, c3, c3}, a4 = {v4, v4, v4, v4};
        PASS2(a0, a1, aR, aZ, a3, W1);                 // Whh0.h0 -> gh
        pollge(bprog, (uint)(first ? i_ - 1 : i_));
        if (!first) {   // rank-1 head fold: W'.h1(d-1) -> r,z,gi
          const half8 b0 = ldh8(&s1[p][c][q * 8]);
          const half8 b1 = ldh8(&s1[p][c][32 + q * 8]);
          PASS2(b0, b1, aR, aZ, a4, W2);
        }
        #pragma unroll
        for (int r4 = 0; r4 < 4; r4++) {
          const float gr = sigm(aR[r4]);
          const float gz = sigm(aZ[r4]);
          const float nn = tanh_fast(a4[r4] + gr * a3[r4]);
          const float hn = nn + gz * (hr[r4] - nn);
          hr[r4] = hn;
          s0[pn][q * 4 + r4][u] = (_Float16)hn;
        }
        asm volatile("s_waitcnt lgkmcnt(0)" ::: "memory");
        *myslot = (uint)(i_ + 1);
      }
    }
  } else {
    // =========================== group B: layer 1 ===========================
    const float ob = outB[0];
    float wk[2][8];
    #pragma unroll
    for (int kt = 0; kt < 2; kt++)
      #pragma unroll
      for (int j = 0; j < 8; j++) wk[kt][j] = outW[kt * 32 + q * 8 + j];

    for (int i = 0; i < TSEQ; i += 2) {
      #pragma unroll
      for (int h2 = 0; h2 < 2; h2++) {
        const int i_ = i + h2, p = h2, pn = h2 ^ 1;
        pollge(bprog, (uint)i_);                       // peers' h1(i_-1)
        const half8 f0 = ldh8(&s1[p][c][q * 8]);
        const half8 f1 = ldh8(&s1[p][c][32 + q * 8]);
        floatx4 aR = {cR, cR, cR, cR}, aZ = {cZ, cZ, cZ, cZ};
        floatx4 a3 = {c3, c3, c3, c3}, a4 = {c4, c4, c4, c4};
        PASS2(f0, f1, aR, aZ, a4, W2);                 // Whh1.h1 -> gh
        pollge(aprog, (uint)(i_ + 1));                 // h0(i_) ready
        const half8 g0 = ldh8(&s0[pn][c][q * 8]);
        const half8 g1 = ldh8(&s0[pn][c][32 + q * 8]);
        PASS2(g0, g1, aR, aZ, a3, W1);                 // Wih1.h0 -> gi
        #pragma unroll
        for (int r4 = 0; r4 < 4; r4++) {
          const float gr = sigm(aR[r4]);
          const float gz = sigm(aZ[r4]);
          const float nn = tanh_fast(a3[r4] + gr * a4[r4]);
          const float hn = nn + gz * (hr[r4] - nn);
          hr[r4] = hn;
          s1[pn][q * 4 + r4][u] = (_Float16)hn;
        }
        asm volatile("s_waitcnt lgkmcnt(0)" ::: "memory");
        *myslot = (uint)(i_ + 1);
      }
    }
    loadW64(dWih1, W1); loadW64(dWhh1, W2);
    cR = dbih1[u] + dbhh1[u];
    cZ = dbih1[64 + u] + dbhh1[64 + u];
    c3 = dbih1[128 + u]; c4 = dbhh1[128 + u];
    for (int i = TSEQ; i < TSEQ + TDEC; i += 2) {
      #pragma unroll
      for (int h2 = 0; h2 < 2; h2++) {
        const int i_ = i + h2, p = h2, pn = h2 ^ 1;
        pollge(bprog, (uint)i_);
        const half8 f0 = ldh8(&s1[p][c][q * 8]);
        const half8 f1 = ldh8(&s1[p][c][32 + q * 8]);
        floatx4 aR = {cR, cR, cR, cR}, aZ = {cZ, cZ, cZ, cZ};
        floatx4 a3 = {c3, c3, c3, c3}, a4 = {c4, c4, c4, c4};
        PASS2(f0, f1, aR, aZ, a4, W2);                 // Whh1.h1 -> gh
        if (wvL == 0 && i_ > TSEQ) {   // head: cv(d) from h1(i_-1) fragments (off critical path)
          float cv = 0.0f;
          #pragma unroll
          for (int j = 0; j < 8; j++) {
            cv = fmaf((float)f0[j], wk[0][j], cv);
            cv = fmaf((float)f1[j], wk[1][j], cv);
          }
          cv += __shfl_xor(cv, 16);
          cv += __shfl_xor(cv, 32);
          if (lane < 16) out[(base + lane) * TDEC + (i_ - TSEQ - 1)] = cv + ob;
        }
        pollge(aprog, (uint)(i_ + 1));
        const half8 g0 = ldh8(&s0[pn][c][q * 8]);
        const half8 g1 = ldh8(&s0[pn][c][32 + q * 8]);
        PASS2(g0, g1, aR, aZ, a3, W1);                 // Wih1.h0 -> gi
        #pragma unroll
        for (int r4 = 0; r4 < 4; r4++) {
          const float gr = sigm(aR[r4]);
          const float gz = sigm(aZ[r4]);
          const float nn = tanh_fast(a3[r4] + gr * a4[r4]);
          const float hn = nn + gz * (hr[r4] - nn);
          hr[r4] = hn;
          s1[pn][q * 4 + r4][u] = (_Float16)hn;
        }
        asm volatile("s_waitcnt lgkmcnt(0)" ::: "memory");
        *myslot = (uint)(i_ + 1);
      }
    }
    // final head value: cv(179) from h1(435) in s1[0]
    if (wvL == 0) {
      pollge(bprog, (uint)(TSEQ + TDEC));
      const half8 f0 = ldh8(&s1[0][c][q * 8]);
      const half8 f1 = ldh8(&s1[0][c][32 + q * 8]);
      float cv = 0.0f;
      #pragma unroll
      for (int j = 0; j < 8; j++) {
        cv = fmaf((float)f0[j], wk[0][j], cv);
        cv = fmaf((float)f1[j], wk[1][j], cv);
      }
      cv += __shfl_xor(cv, 16);
      cv += __shfl_xor(cv, 32);
      if (lane < 16) out[(base + lane) * TDEC + (TDEC - 1)] = cv + ob;
    }
  }
}

extern "C" void kernel_launch(void* const* d_in, const int* in_sizes, int n_in,
                              void* d_out, int out_size, void* d_ws, size_t ws_size,
                              hipStream_t stream) {
  (void)in_sizes; (void)n_in; (void)d_ws; (void)ws_size; (void)out_size;
  const float* x     = (const float*)d_in[0];
  const float* eWih0 = (const float*)d_in[1];
  const float* eWhh0 = (const float*)d_in[2];
  const float* ebih0 = (const float*)d_in[3];
  const float* ebhh0 = (const float*)d_in[4];
  const float* eWih1 = (const float*)d_in[5];
  const float* eWhh1 = (const float*)d_in[6];
  const float* ebih1 = (const float*)d_in[7];
  const float* ebhh1 = (const float*)d_in[8];
  const float* dWih0 = (const float*)d_in[9];
  const float* dWhh0 = (const float*)d_in[10];
  const float* dbih0 = (const float*)d_in[11];
  const float* dbhh0 = (const float*)d_in[12];
  const float* dWih1 = (const float*)d_in[13];
  const float* dWhh1 = (const float*)d_in[14];
  const float* dbih1 = (const float*)d_in[15];
  const float* dbhh1 = (const float*)d_in[16];
  const float* outW  = (const float*)d_in[17];
  const float* outB  = (const float*)d_in[18];
  hipLaunchKernelGGL(gru_persist, dim3(NBLK), dim3(512), 0, stream,
                     x, eWih0, eWhh0, ebih0, ebhh0, eWih1, eWhh1, ebih1, ebhh1,
                     dWih0, dWhh0, dbih0, dbhh0, dWih1, dWhh1, dbih1, dbhh1,
                     outW, outB, (float*)d_out);
}